// Round 1
// baseline (645.856 us; speedup 1.0000x reference)
//
#include <hip/hip_runtime.h>
#include <hip/hip_bf16.h>

typedef short short8 __attribute__((ext_vector_type(8)));
typedef float f32x4 __attribute__((ext_vector_type(4)));
typedef unsigned short u16;
typedef unsigned int u32;

__device__ __forceinline__ u16 bf16rne(float f) {
    u32 u = __float_as_uint(f);
    u32 r = (u + 0x7fffu + ((u >> 16) & 1u)) >> 16;
    return (u16)r;
}
__device__ __forceinline__ float bf2f(u16 s) {
    return __uint_as_float(((u32)s) << 16);
}

// ---------------------------------------------------------------------------
// LDS-only barrier: wave-sync + LDS visibility WITHOUT draining vmcnt.
// __syncthreads() emits s_waitcnt vmcnt(0) before s_barrier, which drains
// fire-and-forget scatter atomics and in-flight prefetch loads. Here only
// lgkmcnt (DS ops) is drained; vmem ops stay outstanding. The "memory"
// clobbers pin LDS reads/writes on the correct side of the barrier.
// ---------------------------------------------------------------------------
__device__ __forceinline__ void ldsbar() {
    asm volatile("s_waitcnt lgkmcnt(0)" ::: "memory");
    __builtin_amdgcn_s_barrier();
    asm volatile("" ::: "memory");
}

// ---------------------------------------------------------------------------
// Weight swizzle into MFMA B-fragment order, bf16. For W[K x 64]:
// frag[i], i = ((nt*KT + kt)*64 + lane)*8 + j
//   = W[kt*32 + (lane>>4)*8 + j][nt*16 + (lane&15)], zero if k >= K.
// ---------------------------------------------------------------------------
__device__ __forceinline__ void swz(const float* __restrict__ src,
                                    u16* __restrict__ dst, int K, int KT,
                                    int tid0, int stride) {
    int total = 4 * KT * 512;
    for (int i = tid0; i < total; i += stride) {
        int j = i & 7, lane = (i >> 3) & 63, g = i >> 9;
        int kt = g % KT;  // nt = g / KT implicit in layout
        int k = kt * 32 + (lane >> 4) * 8 + j;
        int n = (g / KT) * 16 + (lane & 15);
        dst[i] = (k < K) ? bf16rne(src[k * 64 + n]) : (u16)0;
    }
}

__global__ void prep_weights(
    const float* ev1, const float* ev2, const float* ec1, const float* ec2,
    const float* cg1, const float* cg2, const float* cf1, const float* cf2,
    const float* vg1, const float* vg2, const float* vf1, const float* vf2,
    const float* t1,
    u16* dev1, u16* dev2, u16* dec1, u16* dec2, u16* dcg1, u16* dcg2,
    u16* dcf1, u16* dcf2, u16* dvg1, u16* dvg2, u16* dvf1, u16* dvf2,
    u16* dt1) {
    int tid0 = blockIdx.x * blockDim.x + threadIdx.x;
    int st = gridDim.x * blockDim.x;
    swz(ev1, dev1, 19, 1, tid0, st);
    swz(ev2, dev2, 64, 2, tid0, st);
    swz(ec1, dec1, 5, 1, tid0, st);
    swz(ec2, dec2, 64, 2, tid0, st);
    swz(cg1, dcg1, 129, 5, tid0, st);
    swz(cg2, dcg2, 64, 2, tid0, st);
    swz(cf1, dcf1, 128, 4, tid0, st);
    swz(cf2, dcf2, 64, 2, tid0, st);
    swz(vg1, dvg1, 129, 5, tid0, st);
    swz(vg2, dvg2, 64, 2, tid0, st);
    swz(vf1, dvf1, 128, 4, tid0, st);
    swz(vf2, dvf2, 64, 2, tid0, st);
    swz(t1, dt1, 64, 2, tid0, st);
}

// ---------------------------------------------------------------------------
// Generic MFMA layer: A[64 x KT*32] (u16, stride SA) @ Wfrag -> relu -> bf16
// into H (stride 72). Wave w owns output cols [16w, 16w+16).
// ---------------------------------------------------------------------------
template <int KT, int SA>
__device__ __forceinline__ void mfma_layer(const u16* __restrict__ Asrc,
                                           const short8* wf, float bv,
                                           u16* __restrict__ Hdst,
                                           int l15, int lq, int w) {
#pragma unroll
    for (int mt = 0; mt < 4; mt++) {
        f32x4 acc = {0.f, 0.f, 0.f, 0.f};
#pragma unroll
        for (int kt = 0; kt < KT; kt++) {
            short8 a = *(const short8*)(Asrc + (mt * 16 + l15) * SA + kt * 32 + lq * 8);
            acc = __builtin_amdgcn_mfma_f32_16x16x32_bf16(a, wf[kt], acc, 0, 0, 0);
        }
#pragma unroll
        for (int r = 0; r < 4; r++)
            Hdst[(mt * 16 + lq * 4 + r) * 72 + w * 16 + l15] =
                bf16rne(fmaxf(acc[r] + bv, 0.f));
    }
}

// ---------------------------------------------------------------------------
// Input node MLP (MFMA): x[KIN] -> 64 -> 64, relu/relu, bf16 out.
// 64 nodes/block; K padded to 32 (1 k-tile). LDS 23.5 KB -> 6 blocks/CU.
// ---------------------------------------------------------------------------
template <int KIN>
__global__ __launch_bounds__(256, 6) void node_mlp_in(
    const float* __restrict__ x, int n_nodes,
    const u16* __restrict__ w1s, const float* __restrict__ b1,
    const u16* __restrict__ w2s, const float* __restrict__ b2,
    u16* __restrict__ outbf) {
    __shared__ __align__(16) u16 A[64 * 40];
    __shared__ __align__(16) u16 H1[64 * 72];
    __shared__ __align__(16) u16 H2[64 * 72];
    int tid = threadIdx.x, l = tid & 63, w = tid >> 6;
    int l15 = l & 15, lq = l >> 4;
    int blk0 = blockIdx.x * 64;
    // zero pad cols [KIN,40)
    const int PW = 40 - KIN;
    for (int i = tid; i < 64 * PW; i += 256) {
        int r = i / PW, cc = KIN + (i - r * PW);
        A[r * 40 + cc] = 0;
    }
    // fill data cols
    for (int i = tid; i < 64 * KIN; i += 256) {
        int r = i / KIN, k = i - r * KIN;
        int gn = blk0 + r; if (gn >= n_nodes) gn = n_nodes - 1;
        A[r * 40 + k] = bf16rne(x[(size_t)gn * KIN + k]);
    }
    short8 w1f[1], w2f[2];
    w1f[0] = *(const short8*)(w1s + ((w * 1 + 0) * 64 + l) * 8);
#pragma unroll
    for (int kt = 0; kt < 2; kt++)
        w2f[kt] = *(const short8*)(w2s + ((w * 2 + kt) * 64 + l) * 8);
    float b1v = b1[w * 16 + l15], b2v = b2[w * 16 + l15];
    ldsbar();
    mfma_layer<1, 40>(A, w1f, b1v, H1, l15, lq, w);
    ldsbar();
    mfma_layer<2, 72>(H1, w2f, b2v, H2, l15, lq, w);
    ldsbar();
    for (int i = tid; i < 512; i += 256) {
        int r = i >> 3, c = i & 7;
        if (blk0 + r < n_nodes)
            *(uint4*)(outbf + (size_t)(blk0 + r) * 64 + c * 8) =
                *(const uint4*)(H2 + r * 72 + c * 8);
    }
}

// ---------------------------------------------------------------------------
// Shared staging for f-MLPs: A[64 x 200] bf16 = [u(64) | agg_hi(64) |
// agg_residual(64) | 8 pad]; residual keeps agg at ~fp32 precision through
// layer 1 (weight fragments for k-tiles 4,5 reuse k-tiles 2,3).
// ---------------------------------------------------------------------------
__device__ __forceinline__ void stage_concat_res(
    const u16* __restrict__ ubf, const float* __restrict__ agg,
    int blk0, int n_nodes, u16* __restrict__ A, int tid) {
    for (int i = tid; i < 64 * 24; i += 256) {
        int nd = i / 24, c = i - nd * 24;
        int gn = blk0 + nd; if (gn >= n_nodes) gn = n_nodes - 1;
        if (c < 8) {
            *(uint4*)(A + nd * 200 + c * 8) =
                *(const uint4*)(ubf + (size_t)gn * 64 + c * 8);
        } else {
            int q = c - 8;
            float4 av = *(const float4*)(agg + (size_t)gn * 64 + q * 4);
            u16 h0 = bf16rne(av.x), h1 = bf16rne(av.y);
            u16 h2 = bf16rne(av.z), h3 = bf16rne(av.w);
            uint2 hi;
            hi.x = (u32)h0 | ((u32)h1 << 16);
            hi.y = (u32)h2 | ((u32)h3 << 16);
            *(uint2*)(A + nd * 200 + 64 + q * 4) = hi;
            uint2 rs;
            rs.x = (u32)bf16rne(av.x - bf2f(h0)) | ((u32)bf16rne(av.y - bf2f(h1)) << 16);
            rs.y = (u32)bf16rne(av.z - bf2f(h2)) | ((u32)bf16rne(av.w - bf2f(h3)) << 16);
            *(uint2*)(A + nd * 200 + 128 + q * 4) = rs;
        }
    }
}

// ---------------------------------------------------------------------------
// c-side f-MLP (MFMA): concat(c1, agg_hi, agg_res) -> 64 -> 64, bf16 out.
// L2 output staged C-layout into the (dead) A region, then coalesced store.
// LDS 34 KB -> 4 blocks/CU.
// ---------------------------------------------------------------------------
__global__ __launch_bounds__(256, 4) void node_mlp_f(
    const u16* __restrict__ ubf, const float* __restrict__ agg, int n_nodes,
    const u16* __restrict__ w1s, const float* __restrict__ b1,
    const u16* __restrict__ w2s, const float* __restrict__ b2,
    u16* __restrict__ outbf) {
    __shared__ __align__(16) u16 A[64 * 200];
    __shared__ __align__(16) u16 H1[64 * 72];
    int tid = threadIdx.x, l = tid & 63, w = tid >> 6;
    int l15 = l & 15, lq = l >> 4;
    int blk0 = blockIdx.x * 64;
    stage_concat_res(ubf, agg, blk0, n_nodes, A, tid);
    short8 w1f[6], w2f[2];
#pragma unroll
    for (int kt = 0; kt < 4; kt++)
        w1f[kt] = *(const short8*)(w1s + ((w * 4 + kt) * 64 + l) * 8);
    w1f[4] = w1f[2];   // residual cols reuse W1 rows 64..127
    w1f[5] = w1f[3];
#pragma unroll
    for (int kt = 0; kt < 2; kt++)
        w2f[kt] = *(const short8*)(w2s + ((w * 2 + kt) * 64 + l) * 8);
    float b1v = b1[w * 16 + l15], b2v = b2[w * 16 + l15];
    ldsbar();
    mfma_layer<6, 200>(A, w1f, b1v, H1, l15, lq, w);
    ldsbar();
    mfma_layer<2, 72>(H1, w2f, b2v, A, l15, lq, w);   // A region dead: reuse
    ldsbar();
    for (int i = tid; i < 512; i += 256) {
        int r = i >> 3, c = i & 7;
        if (blk0 + r < n_nodes)
            *(uint4*)(outbf + (size_t)(blk0 + r) * 64 + c * 8) =
                *(const uint4*)(A + r * 72 + c * 8);
    }
}

// ---------------------------------------------------------------------------
// v-side f-MLP + tail (MFMA): concat(v1,agg_hi,agg_res)->64->64 (=v2),
// tail L1 MFMA -> f32 LDS, tail L2 (N=8) VALU f32 + sigmoid.
// LDS 44 KB -> 3 blocks/CU.
// ---------------------------------------------------------------------------
__global__ __launch_bounds__(256, 3) void node_mlp_vf_tail(
    const u16* __restrict__ vbf, const float* __restrict__ agg, int n_nodes,
    const u16* __restrict__ w1s, const float* __restrict__ b1,
    const u16* __restrict__ w2s, const float* __restrict__ b2,
    const u16* __restrict__ t1s, const float* __restrict__ tb1,
    const float* __restrict__ tw2, const float* __restrict__ tb2,
    float* __restrict__ out) {
    __shared__ __align__(16) char smem[64 * 200 * 2 + 2 * 64 * 72 * 2];
    u16* A = (u16*)smem;            // 25600 B; later reused as XF (f32)
    float* XF = (float*)smem;       // stride 65 (16640 B <= 25600)
    u16* H1 = (u16*)(smem + 25600);
    u16* H2 = (u16*)(smem + 25600 + 9216);
    int tid = threadIdx.x, l = tid & 63, w = tid >> 6;
    int l15 = l & 15, lq = l >> 4;
    int blk0 = blockIdx.x * 64;
    stage_concat_res(vbf, agg, blk0, n_nodes, A, tid);
    short8 w1f[6], w2f[2], t1f[2];
#pragma unroll
    for (int kt = 0; kt < 4; kt++)
        w1f[kt] = *(const short8*)(w1s + ((w * 4 + kt) * 64 + l) * 8);
    w1f[4] = w1f[2];
    w1f[5] = w1f[3];
#pragma unroll
    for (int kt = 0; kt < 2; kt++) {
        w2f[kt] = *(const short8*)(w2s + ((w * 2 + kt) * 64 + l) * 8);
        t1f[kt] = *(const short8*)(t1s + ((w * 2 + kt) * 64 + l) * 8);
    }
    float b1v = b1[w * 16 + l15], b2v = b2[w * 16 + l15];
    float tb1v = tb1[w * 16 + l15];
    ldsbar();
    mfma_layer<6, 200>(A, w1f, b1v, H1, l15, lq, w);
    ldsbar();
    mfma_layer<2, 72>(H1, w2f, b2v, H2, l15, lq, w);   // v2 (relu, bf16)
    ldsbar();
    // tail layer 1: H2 @ t1f -> relu -> f32 XF (A region dead since L1)
#pragma unroll
    for (int mt = 0; mt < 4; mt++) {
        f32x4 acc = {0.f, 0.f, 0.f, 0.f};
#pragma unroll
        for (int kt = 0; kt < 2; kt++) {
            short8 a = *(const short8*)(H2 + (mt * 16 + l15) * 72 + kt * 32 + lq * 8);
            acc = __builtin_amdgcn_mfma_f32_16x16x32_bf16(a, t1f[kt], acc, 0, 0, 0);
        }
#pragma unroll
        for (int r = 0; r < 4; r++)
            XF[(mt * 16 + lq * 4 + r) * 65 + w * 16 + l15] =
                fmaxf(acc[r] + tb1v, 0.f);
    }
    ldsbar();
    // tail layer 2: wave w computes out cols {2w,2w+1}; f32 VALU; sigmoid
    float s0 = tb2[2 * w], s1 = tb2[2 * w + 1];
    for (int k = 0; k < 64; k++) {
        float xk = XF[l * 65 + k];
        float2 wp = *(const float2*)(tw2 + k * 8 + 2 * w);
        s0 = fmaf(xk, wp.x, s0);
        s1 = fmaf(xk, wp.y, s1);
    }
    if (blk0 + l < n_nodes) {
        float2 r;
        r.x = 1.f / (1.f + __expf(-s0));
        r.y = 1.f / (1.f + __expf(-s1));
        *(float2*)(out + (size_t)(blk0 + l) * 8 + 2 * w) = r;
    }
}

// ---------------------------------------------------------------------------
// Edge conv, R5: 2-deep software pipeline (idx prefetched 2 tiles ahead,
// feature gathers 1 tile ahead into regs) + LDS-only barriers so the
// 16 scatter-atomics/thread and prefetch loads stay in flight across
// barriers (vmcnt retires in issue order -> the staged-reg waits don't
// chain on later-issued atomics). 5 blocks/CU (LDS 30720*5 = 150 KB).
// ---------------------------------------------------------------------------
#define AROW 168
#define HROW 72

__global__ __launch_bounds__(256, 5) void edge_conv(
    const u16* __restrict__ u_feat, const u16* __restrict__ v_feat,
    const int* __restrict__ u_idx, const int* __restrict__ v_idx,
    const float* __restrict__ e_val,
    const u16* __restrict__ w1s, const u16* __restrict__ w2s,
    const float* __restrict__ b1, const float* __restrict__ b2,
    float* __restrict__ agg, int n_tiles) {
    __shared__ __align__(16) u16 A[64 * AROW];
    __shared__ __align__(16) u16 Hs[64 * HROW];

    int tid = threadIdx.x;
    int lane = tid & 63;
    int w = tid >> 6;
    int l15 = lane & 15, lq = lane >> 4;
    int cch = tid & 15, e0 = tid >> 4;

    // zero pad cols [129,168) once; stage only rewrites cols [0,129)
    for (int i = tid; i < 64 * (AROW - 129); i += 256) {
        int r = i / (AROW - 129);
        int cc = 129 + (i - r * (AROW - 129));
        A[r * AROW + cc] = 0;
    }

    short8 w1f[5], w2f[2];
#pragma unroll
    for (int kt = 0; kt < 5; kt++)
        w1f[kt] = *(const short8*)(w1s + ((w * 5 + kt) * 64 + lane) * 8);
#pragma unroll
    for (int kt = 0; kt < 2; kt++)
        w2f[kt] = *(const short8*)(w2s + ((w * 2 + kt) * 64 + lane) * 8);
    float b1v = b1[w * 16 + l15];
    float b2v = b2[w * 16 + l15];

    const int gcol = (cch < 8) ? cch * 8 : 64 + (cch - 8) * 8;
    const u16* fbase = (cch < 8) ? u_feat : v_feat;
    const int* ibase = (cch < 8) ? u_idx : v_idx;
    const int coff = (cch & 7) * 8;

    const int G = gridDim.x;
    int tile = (int)blockIdx.x;

    uint4 st[4];   // staged features for current tile (loaded 1 iter ahead)
    float ev[4];   // staged e_val (cch==0 lanes only)
    int nidx[4];   // gather indices for NEXT tile (loaded 2 iters ahead)

    if (tile < n_tiles) {
#pragma unroll
        for (int t = 0; t < 4; t++) {
            int ge = tile * 64 + e0 + t * 16;
            int ix = ibase[ge];
            st[t] = *(const uint4*)(fbase + (size_t)ix * 64 + coff);
            if (cch == 0) ev[t] = e_val[ge];
        }
        int ntp = tile + G;
        if (ntp < n_tiles) {
#pragma unroll
            for (int t = 0; t < 4; t++) nidx[t] = ibase[ntp * 64 + e0 + t * 16];
        }
    }
    ldsbar();

    for (; tile < n_tiles; tile += G) {
        // commit staged regs to LDS (cols 0..128)
#pragma unroll
        for (int t = 0; t < 4; t++) {
            int e = e0 + t * 16;
            *(uint4*)(&A[e * AROW + gcol]) = st[t];
            if (cch == 0) A[e * AROW + 128] = bf16rne(ev[t]);
        }
        // issue next tile's gathers (indices already in regs) and the
        // tile-after-next's index loads; all overlap B1+L1+B2+L2
        int nt = tile + G;
        if (nt < n_tiles) {
#pragma unroll
            for (int t = 0; t < 4; t++) {
                st[t] = *(const uint4*)(fbase + (size_t)nidx[t] * 64 + coff);
                if (cch == 0) ev[t] = e_val[nt * 64 + e0 + t * 16];
            }
            int nt2 = nt + G;
            if (nt2 < n_tiles) {
#pragma unroll
                for (int t = 0; t < 4; t++)
                    nidx[t] = ibase[nt2 * 64 + e0 + t * 16];
            }
        }
        ldsbar();  // B1: A staged (LDS only; atomics/prefetch stay in flight)

#pragma unroll
        for (int mt = 0; mt < 4; mt++) {
            short8 a1[5];
#pragma unroll
            for (int kt = 0; kt < 5; kt++)
                a1[kt] = *(const short8*)(&A[(mt * 16 + l15) * AROW + kt * 32 + lq * 8]);
            f32x4 acc = {0.f, 0.f, 0.f, 0.f};
#pragma unroll
            for (int kt = 0; kt < 5; kt++)
                acc = __builtin_amdgcn_mfma_f32_16x16x32_bf16(a1[kt], w1f[kt], acc, 0, 0, 0);
#pragma unroll
            for (int r = 0; r < 4; r++) {
                float hv = fmaxf(acc[r] + b1v, 0.f);
                Hs[(mt * 16 + lq * 4 + r) * HROW + w * 16 + l15] = bf16rne(hv);
            }
        }
        ldsbar();  // B2: Hs ready; also guarantees all A reads done

#pragma unroll
        for (int mt = 0; mt < 4; mt++) {
            short8 a2[2];
#pragma unroll
            for (int kt = 0; kt < 2; kt++)
                a2[kt] = *(const short8*)(&Hs[(mt * 16 + l15) * HROW + kt * 32 + lq * 8]);
            f32x4 acc = {0.f, 0.f, 0.f, 0.f};
#pragma unroll
            for (int kt = 0; kt < 2; kt++)
                acc = __builtin_amdgcn_mfma_f32_16x16x32_bf16(a2[kt], w2f[kt], acc, 0, 0, 0);
            int4 ue4 = *(const int4*)(u_idx + tile * 64 + mt * 16 + lq * 4);
            int uearr[4] = {ue4.x, ue4.y, ue4.z, ue4.w};
#pragma unroll
            for (int r = 0; r < 4; r++) {
                float gv = fmaxf(acc[r] + b2v, 0.f);
                __hip_atomic_fetch_add(&agg[(size_t)uearr[r] * 64 + w * 16 + l15], gv,
                                       __ATOMIC_RELAXED, __HIP_MEMORY_SCOPE_AGENT);
            }
        }
    }
}

extern "C" void kernel_launch(void* const* d_in, const int* in_sizes, int n_in,
                              void* d_out, int out_size, void* d_ws, size_t ws_size,
                              hipStream_t stream) {
    const float* v        = (const float*)d_in[0];
    const float* c        = (const float*)d_in[1];
    const int*   cons_idx = (const int*)d_in[2];
    const int*   var_idx  = (const int*)d_in[3];
    const float* e_val    = (const float*)d_in[4];
    const float* ev_w1 = (const float*)d_in[5],  *ev_b1 = (const float*)d_in[6];
    const float* ev_w2 = (const float*)d_in[7],  *ev_b2 = (const float*)d_in[8];
    const float* ec_w1 = (const float*)d_in[9],  *ec_b1 = (const float*)d_in[10];
    const float* ec_w2 = (const float*)d_in[11], *ec_b2 = (const float*)d_in[12];
    const float* cg_w1 = (const float*)d_in[13], *cg_b1 = (const float*)d_in[14];
    const float* cg_w2 = (const float*)d_in[15], *cg_b2 = (const float*)d_in[16];
    const float* cf_w1 = (const float*)d_in[17], *cf_b1 = (const float*)d_in[18];
    const float* cf_w2 = (const float*)d_in[19], *cf_b2 = (const float*)d_in[20];
    const float* vg_w1 = (const float*)d_in[21], *vg_b1 = (const float*)d_in[22];
    const float* vg_w2 = (const float*)d_in[23], *vg_b2 = (const float*)d_in[24];
    const float* vf_w1 = (const float*)d_in[25], *vf_b1 = (const float*)d_in[26];
    const float* vf_w2 = (const float*)d_in[27], *vf_b2 = (const float*)d_in[28];
    const float* t_w1  = (const float*)d_in[29], *t_b1  = (const float*)d_in[30];
    const float* t_w2  = (const float*)d_in[31], *t_b2  = (const float*)d_in[32];

    const int NV = in_sizes[0] / 19;
    const int NC = in_sizes[1] / 5;
    const int NE = in_sizes[4];

    char* ws = (char*)d_ws;
    size_t off = 0;
    u16* v1bf = (u16*)(ws + off); off += (size_t)NV * 64 * 2;
    u16* c1bf = (u16*)(ws + off); off += (size_t)NC * 64 * 2;
    u16* c2bf = (u16*)(ws + off); off += (size_t)NC * 64 * 2;
    float* agg_c = (float*)(ws + off); off += (size_t)NC * 64 * 4;
    float* agg_v = (float*)(ws + off); off += (size_t)NV * 64 * 4;
    u16* ev1s = (u16*)(ws + off); off += 2048 * 2;
    u16* ev2s = (u16*)(ws + off); off += 4096 * 2;
    u16* ec1s = (u16*)(ws + off); off += 2048 * 2;
    u16* ec2s = (u16*)(ws + off); off += 4096 * 2;
    u16* cg1s = (u16*)(ws + off); off += 10240 * 2;
    u16* cg2s = (u16*)(ws + off); off += 4096 * 2;
    u16* cf1s = (u16*)(ws + off); off += 8192 * 2;
    u16* cf2s = (u16*)(ws + off); off += 4096 * 2;
    u16* vg1s = (u16*)(ws + off); off += 10240 * 2;
    u16* vg2s = (u16*)(ws + off); off += 4096 * 2;
    u16* vf1s = (u16*)(ws + off); off += 8192 * 2;
    u16* vf2s = (u16*)(ws + off); off += 4096 * 2;
    u16* t1s  = (u16*)(ws + off); off += 4096 * 2;

    prep_weights<<<40, 256, 0, stream>>>(
        ev_w1, ev_w2, ec_w1, ec_w2, cg_w1, cg_w2, cf_w1, cf_w2,
        vg_w1, vg_w2, vf_w1, vf_w2, t_w1,
        ev1s, ev2s, ec1s, ec2s, cg1s, cg2s, cf1s, cf2s,
        vg1s, vg2s, vf1s, vf2s, t1s);

    node_mlp_in<19><<<(NV + 63) / 64, 256, 0, stream>>>(
        v, NV, ev1s, ev_b1, ev2s, ev_b2, v1bf);
    node_mlp_in<5><<<(NC + 63) / 64, 256, 0, stream>>>(
        c, NC, ec1s, ec_b1, ec2s, ec_b2, c1bf);

    hipMemsetAsync(agg_c, 0, (size_t)NC * 64 * 4, stream);
    edge_conv<<<1280, 256, 0, stream>>>(c1bf, v1bf, cons_idx, var_idx, e_val,
                                        cg1s, cg2s, cg_b1, cg_b2, agg_c, NE / 64);
    node_mlp_f<<<(NC + 63) / 64, 256, 0, stream>>>(
        c1bf, agg_c, NC, cf1s, cf_b1, cf2s, cf_b2, c2bf);

    hipMemsetAsync(agg_v, 0, (size_t)NV * 64 * 4, stream);
    edge_conv<<<1280, 256, 0, stream>>>(v1bf, c2bf, var_idx, cons_idx, e_val,
                                        vg1s, vg2s, vg_b1, vg_b2, agg_v, NE / 64);
    node_mlp_vf_tail<<<(NV + 63) / 64, 256, 0, stream>>>(
        v1bf, agg_v, NV, vf1s, vf_b1, vf2s, vf_b2,
        t1s, t_b1, t_w2, t_b2, (float*)d_out);
}

// Round 2
// 642.656 us; speedup vs baseline: 1.0050x; 1.0050x over previous
//
#include <hip/hip_runtime.h>
#include <hip/hip_bf16.h>

typedef short short8 __attribute__((ext_vector_type(8)));
typedef float f32x4 __attribute__((ext_vector_type(4)));
typedef unsigned short u16;
typedef unsigned int u32;

__device__ __forceinline__ u16 bf16rne(float f) {
    u32 u = __float_as_uint(f);
    u32 r = (u + 0x7fffu + ((u >> 16) & 1u)) >> 16;
    return (u16)r;
}
__device__ __forceinline__ float bf2f(u16 s) {
    return __uint_as_float(((u32)s) << 16);
}

// LDS-only barrier: wave-sync + LDS visibility WITHOUT draining vmcnt, so
// scatter atomics and prefetch loads stay in flight across barriers.
__device__ __forceinline__ void ldsbar() {
    asm volatile("s_waitcnt lgkmcnt(0)" ::: "memory");
    __builtin_amdgcn_s_barrier();
    asm volatile("" ::: "memory");
}

// ---------------------------------------------------------------------------
// Weight swizzle into MFMA B-fragment order, bf16 (unchanged).
// ---------------------------------------------------------------------------
__device__ __forceinline__ void swz(const float* __restrict__ src,
                                    u16* __restrict__ dst, int K, int KT,
                                    int tid0, int stride) {
    int total = 4 * KT * 512;
    for (int i = tid0; i < total; i += stride) {
        int j = i & 7, lane = (i >> 3) & 63, g = i >> 9;
        int kt = g % KT;
        int k = kt * 32 + (lane >> 4) * 8 + j;
        int n = (g / KT) * 16 + (lane & 15);
        dst[i] = (k < K) ? bf16rne(src[k * 64 + n]) : (u16)0;
    }
}

__global__ void prep_weights(
    const float* ev1, const float* ev2, const float* ec1, const float* ec2,
    const float* cg1, const float* cg2, const float* cf1, const float* cf2,
    const float* vg1, const float* vg2, const float* vf1, const float* vf2,
    const float* t1,
    u16* dev1, u16* dev2, u16* dec1, u16* dec2, u16* dcg1, u16* dcg2,
    u16* dcf1, u16* dcf2, u16* dvg1, u16* dvg2, u16* dvf1, u16* dvf2,
    u16* dt1) {
    int tid0 = blockIdx.x * blockDim.x + threadIdx.x;
    int st = gridDim.x * blockDim.x;
    swz(ev1, dev1, 19, 1, tid0, st);
    swz(ev2, dev2, 64, 2, tid0, st);
    swz(ec1, dec1, 5, 1, tid0, st);
    swz(ec2, dec2, 64, 2, tid0, st);
    swz(cg1, dcg1, 129, 5, tid0, st);
    swz(cg2, dcg2, 64, 2, tid0, st);
    swz(cf1, dcf1, 128, 4, tid0, st);
    swz(cf2, dcf2, 64, 2, tid0, st);
    swz(vg1, dvg1, 129, 5, tid0, st);
    swz(vg2, dvg2, 64, 2, tid0, st);
    swz(vf1, dvf1, 128, 4, tid0, st);
    swz(vf2, dvf2, 64, 2, tid0, st);
    swz(t1, dt1, 64, 2, tid0, st);
}

// ---------------------------------------------------------------------------
// Counting-sort pipeline: histogram -> 3-kernel exclusive scan -> scatter
// building destination-sorted copies of (dst_idx, src_idx, e_val).
// ---------------------------------------------------------------------------
#define SCAN_CHUNK 4096

__global__ void hist_kernel(const int* __restrict__ idx, int ne,
                            int* __restrict__ cnt) {
    int i = blockIdx.x * blockDim.x + threadIdx.x;
    int st = gridDim.x * blockDim.x;
    for (; i < ne; i += st) atomicAdd(&cnt[idx[i]], 1);
}

__global__ void scan_part(const int* __restrict__ cnt, int nd,
                          int* __restrict__ bsum) {
    __shared__ int sred[256];
    int b = blockIdx.x, t = threadIdx.x;
    int base = b * SCAN_CHUNK + t * 16;
    int s = 0;
#pragma unroll
    for (int j = 0; j < 16; j++) {
        int i = base + j;
        if (i < nd) s += cnt[i];
    }
    sred[t] = s;
    __syncthreads();
    for (int o = 128; o > 0; o >>= 1) {
        if (t < o) sred[t] += sred[t + o];
        __syncthreads();
    }
    if (t == 0) bsum[b] = sred[0];
}

__global__ void scan_bsum(int* bsum, int nb) {
    if (threadIdx.x == 0 && blockIdx.x == 0) {
        int run = 0;
        for (int i = 0; i < nb; i++) {
            int v = bsum[i];
            bsum[i] = run;
            run += v;
        }
    }
}

__global__ void scan_final(const int* __restrict__ cnt, int nd,
                           const int* __restrict__ bsum,
                           int* __restrict__ cursor) {
    __shared__ int sa[256];
    int b = blockIdx.x, t = threadIdx.x;
    int base = b * SCAN_CHUNK + t * 16;
    int loc[16];
    int s = 0;
#pragma unroll
    for (int j = 0; j < 16; j++) {
        int i = base + j;
        int v = (i < nd) ? cnt[i] : 0;
        loc[j] = s;
        s += v;
    }
    sa[t] = s;
    __syncthreads();
    int inc = s;
    for (int o = 1; o < 256; o <<= 1) {
        int v = (t >= o) ? sa[t - o] : 0;
        __syncthreads();
        sa[t] += v;
        __syncthreads();
    }
    int off = bsum[b] + sa[t] - inc;
#pragma unroll
    for (int j = 0; j < 16; j++) {
        int i = base + j;
        if (i < nd) cursor[i] = off + loc[j];
    }
}

__global__ void scatter_kernel(const int* __restrict__ d_idx,
                               const int* __restrict__ o_idx,
                               const float* __restrict__ ev, int ne,
                               int* __restrict__ cursor, int* __restrict__ ds,
                               int* __restrict__ os, float* __restrict__ evs) {
    int i = blockIdx.x * blockDim.x + threadIdx.x;
    int st = gridDim.x * blockDim.x;
    for (; i < ne; i += st) {
        int d = d_idx[i];
        int p = atomicAdd(&cursor[d], 1);
        ds[p] = d;
        os[p] = o_idx[i];
        evs[p] = ev[i];
    }
}

// ---------------------------------------------------------------------------
// Generic MFMA layer (unchanged).
// ---------------------------------------------------------------------------
template <int KT, int SA>
__device__ __forceinline__ void mfma_layer(const u16* __restrict__ Asrc,
                                           const short8* wf, float bv,
                                           u16* __restrict__ Hdst,
                                           int l15, int lq, int w) {
#pragma unroll
    for (int mt = 0; mt < 4; mt++) {
        f32x4 acc = {0.f, 0.f, 0.f, 0.f};
#pragma unroll
        for (int kt = 0; kt < KT; kt++) {
            short8 a = *(const short8*)(Asrc + (mt * 16 + l15) * SA + kt * 32 + lq * 8);
            acc = __builtin_amdgcn_mfma_f32_16x16x32_bf16(a, wf[kt], acc, 0, 0, 0);
        }
#pragma unroll
        for (int r = 0; r < 4; r++)
            Hdst[(mt * 16 + lq * 4 + r) * 72 + w * 16 + l15] =
                bf16rne(fmaxf(acc[r] + bv, 0.f));
    }
}

// ---------------------------------------------------------------------------
// Input node MLP (unchanged).
// ---------------------------------------------------------------------------
template <int KIN>
__global__ __launch_bounds__(256, 6) void node_mlp_in(
    const float* __restrict__ x, int n_nodes,
    const u16* __restrict__ w1s, const float* __restrict__ b1,
    const u16* __restrict__ w2s, const float* __restrict__ b2,
    u16* __restrict__ outbf) {
    __shared__ __align__(16) u16 A[64 * 40];
    __shared__ __align__(16) u16 H1[64 * 72];
    __shared__ __align__(16) u16 H2[64 * 72];
    int tid = threadIdx.x, l = tid & 63, w = tid >> 6;
    int l15 = l & 15, lq = l >> 4;
    int blk0 = blockIdx.x * 64;
    const int PW = 40 - KIN;
    for (int i = tid; i < 64 * PW; i += 256) {
        int r = i / PW, cc = KIN + (i - r * PW);
        A[r * 40 + cc] = 0;
    }
    for (int i = tid; i < 64 * KIN; i += 256) {
        int r = i / KIN, k = i - r * KIN;
        int gn = blk0 + r; if (gn >= n_nodes) gn = n_nodes - 1;
        A[r * 40 + k] = bf16rne(x[(size_t)gn * KIN + k]);
    }
    short8 w1f[1], w2f[2];
    w1f[0] = *(const short8*)(w1s + ((w * 1 + 0) * 64 + l) * 8);
#pragma unroll
    for (int kt = 0; kt < 2; kt++)
        w2f[kt] = *(const short8*)(w2s + ((w * 2 + kt) * 64 + l) * 8);
    float b1v = b1[w * 16 + l15], b2v = b2[w * 16 + l15];
    ldsbar();
    mfma_layer<1, 40>(A, w1f, b1v, H1, l15, lq, w);
    ldsbar();
    mfma_layer<2, 72>(H1, w2f, b2v, H2, l15, lq, w);
    ldsbar();
    for (int i = tid; i < 512; i += 256) {
        int r = i >> 3, c = i & 7;
        if (blk0 + r < n_nodes)
            *(uint4*)(outbf + (size_t)(blk0 + r) * 64 + c * 8) =
                *(const uint4*)(H2 + r * 72 + c * 8);
    }
}

// ---------------------------------------------------------------------------
// f-MLP staging (unchanged).
// ---------------------------------------------------------------------------
__device__ __forceinline__ void stage_concat_res(
    const u16* __restrict__ ubf, const float* __restrict__ agg,
    int blk0, int n_nodes, u16* __restrict__ A, int tid) {
    for (int i = tid; i < 64 * 24; i += 256) {
        int nd = i / 24, c = i - nd * 24;
        int gn = blk0 + nd; if (gn >= n_nodes) gn = n_nodes - 1;
        if (c < 8) {
            *(uint4*)(A + nd * 200 + c * 8) =
                *(const uint4*)(ubf + (size_t)gn * 64 + c * 8);
        } else {
            int q = c - 8;
            float4 av = *(const float4*)(agg + (size_t)gn * 64 + q * 4);
            u16 h0 = bf16rne(av.x), h1 = bf16rne(av.y);
            u16 h2 = bf16rne(av.z), h3 = bf16rne(av.w);
            uint2 hi;
            hi.x = (u32)h0 | ((u32)h1 << 16);
            hi.y = (u32)h2 | ((u32)h3 << 16);
            *(uint2*)(A + nd * 200 + 64 + q * 4) = hi;
            uint2 rs;
            rs.x = (u32)bf16rne(av.x - bf2f(h0)) | ((u32)bf16rne(av.y - bf2f(h1)) << 16);
            rs.y = (u32)bf16rne(av.z - bf2f(h2)) | ((u32)bf16rne(av.w - bf2f(h3)) << 16);
            *(uint2*)(A + nd * 200 + 128 + q * 4) = rs;
        }
    }
}

// ---------------------------------------------------------------------------
// c-side f-MLP (unchanged).
// ---------------------------------------------------------------------------
__global__ __launch_bounds__(256, 4) void node_mlp_f(
    const u16* __restrict__ ubf, const float* __restrict__ agg, int n_nodes,
    const u16* __restrict__ w1s, const float* __restrict__ b1,
    const u16* __restrict__ w2s, const float* __restrict__ b2,
    u16* __restrict__ outbf) {
    __shared__ __align__(16) u16 A[64 * 200];
    __shared__ __align__(16) u16 H1[64 * 72];
    int tid = threadIdx.x, l = tid & 63, w = tid >> 6;
    int l15 = l & 15, lq = l >> 4;
    int blk0 = blockIdx.x * 64;
    stage_concat_res(ubf, agg, blk0, n_nodes, A, tid);
    short8 w1f[6], w2f[2];
#pragma unroll
    for (int kt = 0; kt < 4; kt++)
        w1f[kt] = *(const short8*)(w1s + ((w * 4 + kt) * 64 + l) * 8);
    w1f[4] = w1f[2];
    w1f[5] = w1f[3];
#pragma unroll
    for (int kt = 0; kt < 2; kt++)
        w2f[kt] = *(const short8*)(w2s + ((w * 2 + kt) * 64 + l) * 8);
    float b1v = b1[w * 16 + l15], b2v = b2[w * 16 + l15];
    ldsbar();
    mfma_layer<6, 200>(A, w1f, b1v, H1, l15, lq, w);
    ldsbar();
    mfma_layer<2, 72>(H1, w2f, b2v, A, l15, lq, w);
    ldsbar();
    for (int i = tid; i < 512; i += 256) {
        int r = i >> 3, c = i & 7;
        if (blk0 + r < n_nodes)
            *(uint4*)(outbf + (size_t)(blk0 + r) * 64 + c * 8) =
                *(const uint4*)(A + r * 72 + c * 8);
    }
}

// ---------------------------------------------------------------------------
// v-side f-MLP + tail (unchanged).
// ---------------------------------------------------------------------------
__global__ __launch_bounds__(256, 3) void node_mlp_vf_tail(
    const u16* __restrict__ vbf, const float* __restrict__ agg, int n_nodes,
    const u16* __restrict__ w1s, const float* __restrict__ b1,
    const u16* __restrict__ w2s, const float* __restrict__ b2,
    const u16* __restrict__ t1s, const float* __restrict__ tb1,
    const float* __restrict__ tw2, const float* __restrict__ tb2,
    float* __restrict__ out) {
    __shared__ __align__(16) char smem[64 * 200 * 2 + 2 * 64 * 72 * 2];
    u16* A = (u16*)smem;
    float* XF = (float*)smem;
    u16* H1 = (u16*)(smem + 25600);
    u16* H2 = (u16*)(smem + 25600 + 9216);
    int tid = threadIdx.x, l = tid & 63, w = tid >> 6;
    int l15 = l & 15, lq = l >> 4;
    int blk0 = blockIdx.x * 64;
    stage_concat_res(vbf, agg, blk0, n_nodes, A, tid);
    short8 w1f[6], w2f[2], t1f[2];
#pragma unroll
    for (int kt = 0; kt < 4; kt++)
        w1f[kt] = *(const short8*)(w1s + ((w * 4 + kt) * 64 + l) * 8);
    w1f[4] = w1f[2];
    w1f[5] = w1f[3];
#pragma unroll
    for (int kt = 0; kt < 2; kt++) {
        w2f[kt] = *(const short8*)(w2s + ((w * 2 + kt) * 64 + l) * 8);
        t1f[kt] = *(const short8*)(t1s + ((w * 2 + kt) * 64 + l) * 8);
    }
    float b1v = b1[w * 16 + l15], b2v = b2[w * 16 + l15];
    float tb1v = tb1[w * 16 + l15];
    ldsbar();
    mfma_layer<6, 200>(A, w1f, b1v, H1, l15, lq, w);
    ldsbar();
    mfma_layer<2, 72>(H1, w2f, b2v, H2, l15, lq, w);
    ldsbar();
#pragma unroll
    for (int mt = 0; mt < 4; mt++) {
        f32x4 acc = {0.f, 0.f, 0.f, 0.f};
#pragma unroll
        for (int kt = 0; kt < 2; kt++) {
            short8 a = *(const short8*)(H2 + (mt * 16 + l15) * 72 + kt * 32 + lq * 8);
            acc = __builtin_amdgcn_mfma_f32_16x16x32_bf16(a, t1f[kt], acc, 0, 0, 0);
        }
#pragma unroll
        for (int r = 0; r < 4; r++)
            XF[(mt * 16 + lq * 4 + r) * 65 + w * 16 + l15] =
                fmaxf(acc[r] + tb1v, 0.f);
    }
    ldsbar();
    float s0 = tb2[2 * w], s1 = tb2[2 * w + 1];
    for (int k = 0; k < 64; k++) {
        float xk = XF[l * 65 + k];
        float2 wp = *(const float2*)(tw2 + k * 8 + 2 * w);
        s0 = fmaf(xk, wp.x, s0);
        s1 = fmaf(xk, wp.y, s1);
    }
    if (blk0 + l < n_nodes) {
        float2 r;
        r.x = 1.f / (1.f + __expf(-s0));
        r.y = 1.f / (1.f + __expf(-s1));
        *(float2*)(out + (size_t)(blk0 + l) * 8 + 2 * w) = r;
    }
}

// ---------------------------------------------------------------------------
// Edge conv, R6: destination-SORTED edges + in-LDS segmented reduction.
// The g-output tile is written f32 into LDS (overlaying the dead A staging
// region, cols 0..127 only -> zero-pad cols 129..159 preserved), then thread
// t run-reduces rows [16*(t>>6), +16) of column t&63 and emits ONE wave-
// coalesced atomic per destination run (~9x fewer, 64-lane contiguous).
// 4 ldsbars/tile; LDS 30976 B -> 5 blocks/CU.
// ---------------------------------------------------------------------------
#define AROW 168
#define HROW 72

__global__ __launch_bounds__(256, 5) void edge_conv(
    const u16* __restrict__ u_feat, const u16* __restrict__ v_feat,
    const int* __restrict__ ds,   // sorted destination ids   [ne]
    const int* __restrict__ os,   // matching source ids      [ne]
    const float* __restrict__ evs,  // matching edge values   [ne]
    const u16* __restrict__ w1s, const u16* __restrict__ w2s,
    const float* __restrict__ b1, const float* __restrict__ b2,
    float* __restrict__ agg, int n_tiles) {
    __shared__ __align__(16) u16 A[64 * AROW];   // staging; later G (f32) overlay
    __shared__ __align__(16) u16 Hs[64 * HROW];
    __shared__ int Didx[64];

    int tid = threadIdx.x;
    int lane = tid & 63;
    int w = tid >> 6;
    int l15 = lane & 15, lq = lane >> 4;
    int cch = tid & 15, e0 = tid >> 4;

    // zero pad cols [129,168) once; staging rewrites cols [0,129), G overlay
    // touches only cols [0,128) as f32.
    for (int i = tid; i < 64 * (AROW - 129); i += 256) {
        int r = i / (AROW - 129);
        int cc = 129 + (i - r * (AROW - 129));
        A[r * AROW + cc] = 0;
    }

    short8 w1f[5], w2f[2];
#pragma unroll
    for (int kt = 0; kt < 5; kt++)
        w1f[kt] = *(const short8*)(w1s + ((w * 5 + kt) * 64 + lane) * 8);
#pragma unroll
    for (int kt = 0; kt < 2; kt++)
        w2f[kt] = *(const short8*)(w2s + ((w * 2 + kt) * 64 + lane) * 8);
    float b1v = b1[w * 16 + l15];
    float b2v = b2[w * 16 + l15];

    const int gcol = (cch < 8) ? cch * 8 : 64 + (cch - 8) * 8;
    const u16* fbase = (cch < 8) ? u_feat : v_feat;
    const int* ibase = (cch < 8) ? ds : os;
    const int coff = (cch & 7) * 8;

    const int G = gridDim.x;
    int tile = (int)blockIdx.x;

    uint4 st[4];
    float ev[4];
    int nidx[4];
    int didx_c = 0, didx_n = 0;

    if (tile < n_tiles) {
#pragma unroll
        for (int t = 0; t < 4; t++) {
            int ge = tile * 64 + e0 + t * 16;
            int ix = ibase[ge];
            st[t] = *(const uint4*)(fbase + (size_t)ix * 64 + coff);
            if (cch == 0) ev[t] = evs[ge];
        }
        if (tid < 64) didx_c = ds[tile * 64 + tid];
        int ntp = tile + G;
        if (ntp < n_tiles) {
#pragma unroll
            for (int t = 0; t < 4; t++) nidx[t] = ibase[ntp * 64 + e0 + t * 16];
        }
    }

    for (; tile < n_tiles; tile += G) {
        ldsbar();  // B0: prev seg-reduce reads of G done before commit writes
#pragma unroll
        for (int t = 0; t < 4; t++) {
            int e = e0 + t * 16;
            *(uint4*)(&A[e * AROW + gcol]) = st[t];
            if (cch == 0) A[e * AROW + 128] = bf16rne(ev[t]);
        }
        int nt = tile + G;
        if (nt < n_tiles) {
#pragma unroll
            for (int t = 0; t < 4; t++) {
                st[t] = *(const uint4*)(fbase + (size_t)nidx[t] * 64 + coff);
                if (cch == 0) ev[t] = evs[nt * 64 + e0 + t * 16];
            }
            if (tid < 64) didx_n = ds[nt * 64 + tid];
            int nt2 = nt + G;
            if (nt2 < n_tiles) {
#pragma unroll
                for (int t = 0; t < 4; t++)
                    nidx[t] = ibase[nt2 * 64 + e0 + t * 16];
            }
        }
        ldsbar();  // B1: A staged

#pragma unroll
        for (int mt = 0; mt < 4; mt++) {
            short8 a1[5];
#pragma unroll
            for (int kt = 0; kt < 5; kt++)
                a1[kt] = *(const short8*)(&A[(mt * 16 + l15) * AROW + kt * 32 + lq * 8]);
            f32x4 acc = {0.f, 0.f, 0.f, 0.f};
#pragma unroll
            for (int kt = 0; kt < 5; kt++)
                acc = __builtin_amdgcn_mfma_f32_16x16x32_bf16(a1[kt], w1f[kt], acc, 0, 0, 0);
#pragma unroll
            for (int r = 0; r < 4; r++) {
                float hv = fmaxf(acc[r] + b1v, 0.f);
                Hs[(mt * 16 + lq * 4 + r) * HROW + w * 16 + l15] = bf16rne(hv);
            }
        }
        ldsbar();  // B2: Hs ready; A reads done -> A region free for G

        float* Gf = (float*)A;  // row stride 84 floats (=AROW u16); cols 0..63
#pragma unroll
        for (int mt = 0; mt < 4; mt++) {
            short8 a2[2];
#pragma unroll
            for (int kt = 0; kt < 2; kt++)
                a2[kt] = *(const short8*)(&Hs[(mt * 16 + l15) * HROW + kt * 32 + lq * 8]);
            f32x4 acc = {0.f, 0.f, 0.f, 0.f};
#pragma unroll
            for (int kt = 0; kt < 2; kt++)
                acc = __builtin_amdgcn_mfma_f32_16x16x32_bf16(a2[kt], w2f[kt], acc, 0, 0, 0);
#pragma unroll
            for (int r = 0; r < 4; r++)
                Gf[(mt * 16 + lq * 4 + r) * 84 + w * 16 + l15] =
                    fmaxf(acc[r] + b2v, 0.f);
        }
        if (tid < 64) Didx[tid] = didx_c;
        ldsbar();  // B3: G + Didx ready

        // segmented reduce: thread t scans rows [16*(t>>6), +16) of col t&63.
        // Rows are destination-sorted; branch is wave-uniform; each atomic is
        // a full-wave 64-lane op on 256 contiguous bytes.
        {
            int col = tid & 63, rg = tid >> 6;
            int r0 = rg * 16;
            int dcur = Didx[r0];
            float s = Gf[r0 * 84 + col];
#pragma unroll
            for (int r = 1; r < 16; r++) {
                int d = Didx[r0 + r];
                float g = Gf[(r0 + r) * 84 + col];
                if (d != dcur) {
                    __hip_atomic_fetch_add(&agg[(size_t)dcur * 64 + col], s,
                                           __ATOMIC_RELAXED, __HIP_MEMORY_SCOPE_AGENT);
                    dcur = d;
                    s = g;
                } else {
                    s += g;
                }
            }
            __hip_atomic_fetch_add(&agg[(size_t)dcur * 64 + col], s,
                                   __ATOMIC_RELAXED, __HIP_MEMORY_SCOPE_AGENT);
        }
        didx_c = didx_n;
    }
}

extern "C" void kernel_launch(void* const* d_in, const int* in_sizes, int n_in,
                              void* d_out, int out_size, void* d_ws, size_t ws_size,
                              hipStream_t stream) {
    const float* v        = (const float*)d_in[0];
    const float* c        = (const float*)d_in[1];
    const int*   cons_idx = (const int*)d_in[2];
    const int*   var_idx  = (const int*)d_in[3];
    const float* e_val    = (const float*)d_in[4];
    const float* ev_w1 = (const float*)d_in[5],  *ev_b1 = (const float*)d_in[6];
    const float* ev_w2 = (const float*)d_in[7],  *ev_b2 = (const float*)d_in[8];
    const float* ec_w1 = (const float*)d_in[9],  *ec_b1 = (const float*)d_in[10];
    const float* ec_w2 = (const float*)d_in[11], *ec_b2 = (const float*)d_in[12];
    const float* cg_w1 = (const float*)d_in[13], *cg_b1 = (const float*)d_in[14];
    const float* cg_w2 = (const float*)d_in[15], *cg_b2 = (const float*)d_in[16];
    const float* cf_w1 = (const float*)d_in[17], *cf_b1 = (const float*)d_in[18];
    const float* cf_w2 = (const float*)d_in[19], *cf_b2 = (const float*)d_in[20];
    const float* vg_w1 = (const float*)d_in[21], *vg_b1 = (const float*)d_in[22];
    const float* vg_w2 = (const float*)d_in[23], *vg_b2 = (const float*)d_in[24];
    const float* vf_w1 = (const float*)d_in[25], *vf_b1 = (const float*)d_in[26];
    const float* vf_w2 = (const float*)d_in[27], *vf_b2 = (const float*)d_in[28];
    const float* t_w1  = (const float*)d_in[29], *t_b1  = (const float*)d_in[30];
    const float* t_w2  = (const float*)d_in[31], *t_b2  = (const float*)d_in[32];

    const int NV = in_sizes[0] / 19;
    const int NC = in_sizes[1] / 5;
    const int NE = in_sizes[4];

    char* ws = (char*)d_ws;
    size_t off = 0;
    u16* v1bf = (u16*)(ws + off); off += (size_t)NV * 64 * 2;
    u16* c1bf = (u16*)(ws + off); off += (size_t)NC * 64 * 2;
    u16* c2bf = (u16*)(ws + off); off += (size_t)NC * 64 * 2;
    float* agg_c = (float*)(ws + off); off += (size_t)NC * 64 * 4;
    float* agg_v = (float*)(ws + off); off += (size_t)NV * 64 * 4;
    u16* ev1s = (u16*)(ws + off); off += 2048 * 2;
    u16* ev2s = (u16*)(ws + off); off += 4096 * 2;
    u16* ec1s = (u16*)(ws + off); off += 2048 * 2;
    u16* ec2s = (u16*)(ws + off); off += 4096 * 2;
    u16* cg1s = (u16*)(ws + off); off += 10240 * 2;
    u16* cg2s = (u16*)(ws + off); off += 4096 * 2;
    u16* cf1s = (u16*)(ws + off); off += 8192 * 2;
    u16* cf2s = (u16*)(ws + off); off += 4096 * 2;
    u16* vg1s = (u16*)(ws + off); off += 10240 * 2;
    u16* vg2s = (u16*)(ws + off); off += 4096 * 2;
    u16* vf1s = (u16*)(ws + off); off += 8192 * 2;
    u16* vf2s = (u16*)(ws + off); off += 4096 * 2;
    u16* t1s  = (u16*)(ws + off); off += 4096 * 2;
    off = (off + 255) & ~(size_t)255;
    int* cnt    = (int*)(ws + off); off += (size_t)((NV > NC) ? NV : NC) * 4;
    int* cursor = (int*)(ws + off); off += (size_t)((NV > NC) ? NV : NC) * 4;
    int* bsum   = (int*)(ws + off); off += 64 * 4;
    int* ds_e   = (int*)(ws + off); off += (size_t)NE * 4;
    int* os_e   = (int*)(ws + off); off += (size_t)NE * 4;
    float* evs_e = (float*)(ws + off); off += (size_t)NE * 4;

    const int n_tiles = NE / 64;

    prep_weights<<<40, 256, 0, stream>>>(
        ev_w1, ev_w2, ec_w1, ec_w2, cg_w1, cg_w2, cf_w1, cf_w2,
        vg_w1, vg_w2, vf_w1, vf_w2, t_w1,
        ev1s, ev2s, ec1s, ec2s, cg1s, cg2s, cf1s, cf2s,
        vg1s, vg2s, vf1s, vf2s, t1s);

    node_mlp_in<19><<<(NV + 63) / 64, 256, 0, stream>>>(
        v, NV, ev1s, ev_b1, ev2s, ev_b2, v1bf);
    node_mlp_in<5><<<(NC + 63) / 64, 256, 0, stream>>>(
        c, NC, ec1s, ec_b1, ec2s, ec_b2, c1bf);

    // ---- c-side: sort edges by cons_idx, conv, f-MLP ----
    {
        int nd = NC, nb = (nd + SCAN_CHUNK - 1) / SCAN_CHUNK;
        hipMemsetAsync(cnt, 0, (size_t)nd * 4, stream);
        hist_kernel<<<512, 256, 0, stream>>>(cons_idx, NE, cnt);
        scan_part<<<nb, 256, 0, stream>>>(cnt, nd, bsum);
        scan_bsum<<<1, 64, 0, stream>>>(bsum, nb);
        scan_final<<<nb, 256, 0, stream>>>(cnt, nd, bsum, cursor);
        scatter_kernel<<<1024, 256, 0, stream>>>(cons_idx, var_idx, e_val, NE,
                                                 cursor, ds_e, os_e, evs_e);
        hipMemsetAsync(agg_c, 0, (size_t)NC * 64 * 4, stream);
        edge_conv<<<1280, 256, 0, stream>>>(c1bf, v1bf, ds_e, os_e, evs_e,
                                            cg1s, cg2s, cg_b1, cg_b2, agg_c, n_tiles);
        node_mlp_f<<<(NC + 63) / 64, 256, 0, stream>>>(
            c1bf, agg_c, NC, cf1s, cf_b1, cf2s, cf_b2, c2bf);
    }

    // ---- v-side: sort edges by var_idx, conv, f-MLP + tail ----
    {
        int nd = NV, nb = (nd + SCAN_CHUNK - 1) / SCAN_CHUNK;
        hipMemsetAsync(cnt, 0, (size_t)nd * 4, stream);
        hist_kernel<<<512, 256, 0, stream>>>(var_idx, NE, cnt);
        scan_part<<<nb, 256, 0, stream>>>(cnt, nd, bsum);
        scan_bsum<<<1, 64, 0, stream>>>(bsum, nb);
        scan_final<<<nb, 256, 0, stream>>>(cnt, nd, bsum, cursor);
        scatter_kernel<<<1024, 256, 0, stream>>>(var_idx, cons_idx, e_val, NE,
                                                 cursor, ds_e, os_e, evs_e);
        hipMemsetAsync(agg_v, 0, (size_t)NV * 64 * 4, stream);
        edge_conv<<<1280, 256, 0, stream>>>(v1bf, c2bf, ds_e, os_e, evs_e,
                                            vg1s, vg2s, vg_b1, vg_b2, agg_v, n_tiles);
        node_mlp_vf_tail<<<(NV + 63) / 64, 256, 0, stream>>>(
            v1bf, agg_v, NV, vf1s, vf_b1, vf2s, vf_b2,
            t1s, t_b1, t_w2, t_b2, (float*)d_out);
    }
}